// Round 3
// baseline (38.780 us; speedup 1.0000x reference)
//
#include <hip/hip_runtime.h>
#include <stdint.h>

#define HT 56
#define WD 56
#define CH 16
#define FT 16
#define KK 144          // 3*3*16 patch size
#define WAVES 4         // waves per block = pixels per block
#define THREADS 256
#define KPW 160         // padded per-wave key stride (uint32), 16B-aligned

// One wave = one output pixel.
// 32-bit keys: t = m*2^-23 exactly (jax.random.uniform), key = (m<<8)|k,
// so u32 ascending order == stable argsort by t with patch-index tie-break.
// Phase 1: rank-sort via b128 broadcast reads (4 keys/read, u32 compares).
// Phase 2: 64 lanes = 16 features x 4 chunks of 36; pass A decodes chunk once,
//          caches t/w in registers; shfl scan; pass B runs entirely from regs.
__global__ __launch_bounds__(THREADS, 4) void spiking_conv2d_kernel(
    const float* __restrict__ tj,        // [B,56,56,16]
    const float* __restrict__ kern,      // [3,3,16,16] flat [144*16]
    const float* __restrict__ threshold, // [16]
    const float* __restrict__ alpha,     // [16]
    float* __restrict__ out,             // [B,56,56,16]
    int npix)
{
    __shared__ float    sJ[KK * FT];        // 9216 B
    __shared__ uint32_t sKey[WAVES][KPW];   // 2560 B

    const int tid  = threadIdx.x;
    const int wave = tid >> 6;
    const int lane = tid & 63;

    for (int i = tid; i < KK * FT; i += THREADS) sJ[i] = kern[i];
    __syncthreads();                        // the only barrier

    const int n = blockIdx.x * WAVES + wave;
    if (n >= npix) return;

    const int hw  = HT * WD;
    const int bb  = n / hw;
    const int rem = n - bb * hw;
    const int y   = rem / WD;
    const int x   = rem - y * WD;

    auto makeKey = [&](int k) -> uint32_t {
        const int tap = k >> 4;             // di*3+dj
        const int ch  = k & 15;
        const int di  = tap / 3;
        const int dj  = tap - 3 * di;
        const int yy  = y + di - 1;         // 'same' pad
        const int xx  = x + dj - 1;
        float t = 0.0f;                     // T_MIN pad
        if ((unsigned)yy < (unsigned)HT && (unsigned)xx < (unsigned)WD)
            t = tj[(((bb * HT) + yy) * WD + xx) * CH + ch];
        const uint32_t m = (uint32_t)(t * 8388608.0f);   // exact (t = m*2^-23)
        return (m << 8) | (uint32_t)k;
    };

    const uint32_t key0 = makeKey(lane);
    const uint32_t key1 = makeKey(lane + 64);
    const uint32_t key2 = (lane < 16) ? makeKey(lane + 128) : 0xFFFFFFFFu;

    sKey[wave][lane]      = key0;
    sKey[wave][lane + 64] = key1;
    if (lane < 16) sKey[wave][lane + 128] = key2;

    // rank = count of strictly-smaller keys (keys unique: low 8 bits = k)
    int r0 = 0, r1 = 0, r2 = 0;
    {
        const uint4* kp = (const uint4*)(&sKey[wave][0]);
        #pragma unroll 6
        for (int j = 0; j < KK / 4; ++j) {
            const uint4 kj = kp[j];         // broadcast b128 read
            r0 += (kj.x < key0) + (kj.y < key0) + (kj.z < key0) + (kj.w < key0);
            r1 += (kj.x < key1) + (kj.y < key1) + (kj.z < key1) + (kj.w < key1);
            r2 += (kj.x < key2) + (kj.y < key2) + (kj.z < key2) + (kj.w < key2);
        }
    }
    // in-place scatter (register keys survive; same-wave ds ops stay in order)
    sKey[wave][r0] = key0;
    sKey[wave][r1] = key1;
    if (lane < 16) sKey[wave][r2] = key2;

    // ---------------- phase 2: 16 features x 4 chunks of 36 --------------------
    const int f   = lane & 15;
    const int c   = lane >> 4;
    const float thr = threshold[f];
    const float al  = alpha[f];

    // pass A: read chunk (9 x uint4), decode once, cache t/w, partial sums
    float tc[36], wc[36];
    float lN = 0.0f, lD = 0.0f;
    {
        const uint4* kp = (const uint4*)(&sKey[wave][0]) + c * 9;
        #pragma unroll
        for (int j = 0; j < 9; ++j) {
            const uint4 kq = kp[j];
            const uint32_t ks[4] = {kq.x, kq.y, kq.z, kq.w};
            #pragma unroll
            for (int e = 0; e < 4; ++e) {
                const uint32_t kk = ks[e];
                const float t = (float)(kk >> 8) * (1.0f / 8388608.0f);
                const float w = sJ[(kk & 255u) * FT + f];
                tc[4 * j + e] = t;
                wc[4 * j + e] = w;
                lN = fmaf(w, t, lN);
                lD += w;
            }
        }
    }
    // inclusive scan over chunks (lanes with same f), then exclusive prefix
    float iN = lN, iD = lD;
    {
        float sN = __shfl_up(iN, 16), sD = __shfl_up(iD, 16);
        if (c >= 1) { iN += sN; iD += sD; }
        sN = __shfl_up(iN, 32); sD = __shfl_up(iD, 32);
        if (c >= 2) { iN += sN; iD += sD; }
    }
    float num = iN - lN;    // exclusive prefix of cumsum(J*t)
    float den = iD - lD;    // exclusive prefix of cumsum(J)

    // boundary t_next: first t of next chunk (1e6 sentinel for last chunk)
    float tbound = __shfl_down(tc[0], 16);
    if (c == 3) tbound = 1.0e6f;

    // pass B: first-valid select, entirely from registers
    float selN = 0.0f, selD = 1.0f;
    bool  found = false;
    #pragma unroll
    for (int i = 0; i < 36; ++i) {
        const float t  = tc[i];
        const float tn = (i < 35) ? tc[i + 1] : tbound;
        const float w  = wc[i];
        num = fmaf(w, t, num);
        den += w;
        const float numt = num + thr;       // + alpha*T_MIN_PREV (=0)
        const float dena = den + al;
        // valid = (numt/dena < tn) && (dena > 0), division-free
        const bool valid = (dena > 0.0f) && (numt < tn * dena);
        const bool take  = !found && (valid || (c == 0 && i == 0)); // argmax fallback
        if (take) { selN = numt; selD = dena; }
        found = found || valid;
    }
    int pos = found ? c : ((c == 0) ? 6 : 7);   // 6 = chunk0 fallback sentinel

    // min-pos reduce across the 4 chunks of this feature
    {
        int   opos = __shfl_xor(pos, 16);
        float oN   = __shfl_xor(selN, 16);
        float oD   = __shfl_xor(selD, 16);
        if (opos < pos) { pos = opos; selN = oN; selD = oD; }
        opos = __shfl_xor(pos, 32);
        oN   = __shfl_xor(selN, 32);
        oD   = __shfl_xor(selD, 32);
        if (opos < pos) { pos = opos; selN = oN; selD = oD; }
    }
    if (c == 0) {
        const float ti = selN / selD;
        out[n * FT + f] = (ti < 1.0f) ? ti : 1.0f;   // clamp to T_MAX
    }
}

extern "C" void kernel_launch(void* const* d_in, const int* in_sizes, int n_in,
                              void* d_out, int out_size, void* d_ws, size_t ws_size,
                              hipStream_t stream) {
    const float* tj    = (const float*)d_in[0];
    const float* kern  = (const float*)d_in[1];
    const float* thr   = (const float*)d_in[2];
    const float* alpha = (const float*)d_in[3];
    float*       out   = (float*)d_out;

    const int npix   = in_sizes[0] / CH;                  // B*H*W = 12544
    const int blocks = (npix + WAVES - 1) / WAVES;        // 3136
    spiking_conv2d_kernel<<<blocks, THREADS, 0, stream>>>(tj, kern, thr, alpha, out, npix);
}

// Round 4
// 26.632 us; speedup vs baseline: 1.4562x; 1.4562x over previous
//
#include <hip/hip_runtime.h>
#include <stdint.h>

#define HT 56
#define WD 56
#define CH 16
#define FT 16
#define KK 144          // 3*3*16 patch size
#define WAVES 4         // waves per block = pixels per block
#define THREADS 256
#define KPW 160         // padded per-wave key stride (uint32), 16B-aligned
#define INV23 (1.0f / 8388608.0f)

// One wave = one output pixel. 32-bit keys: t = m*2^-23 exactly, key=(m<<8)|k.
// Fast paths (no sort):
//   z==0 (no zero-time inputs): first sorted candidate is the global-min key;
//         validate with the exact reference condition; needs only a two-min reduce.
//   z>0  (padded border): first possibly-valid candidate is the END of the zero
//         block: num=0 exactly, den = sum(J over t==0 entries)+alpha. Zero-block
//         internal order is irrelevant -> sum over UNSORTED keys.
// If any feature fails validation (or thr<0 for z>0), the whole wave runs the
// verified full sort+scan fallback.
__global__ __launch_bounds__(THREADS) void spiking_conv2d_kernel(
    const float* __restrict__ tj,        // [B,56,56,16]
    const float* __restrict__ kern,      // [3,3,16,16] flat [144][16]
    const float* __restrict__ threshold, // [16]
    const float* __restrict__ alpha,     // [16]
    float* __restrict__ out,             // [B,56,56,16]
    int npix)
{
    __shared__ uint32_t sKey[WAVES][KPW];   // 2560 B total

    const int tid  = threadIdx.x;
    const int wave = tid >> 6;
    const int lane = tid & 63;

    const int n = blockIdx.x * WAVES + wave;
    if (n >= npix) return;

    const int hw  = HT * WD;
    const int bb  = n / hw;
    const int rem = n - bb * hw;
    const int y   = rem / WD;
    const int x   = rem - y * WD;

    auto makeKey = [&](int k) -> uint32_t {
        const int tap = k >> 4;             // di*3+dj
        const int ch  = k & 15;
        const int di  = tap / 3;
        const int dj  = tap - 3 * di;
        const int yy  = y + di - 1;         // 'same' pad
        const int xx  = x + dj - 1;
        float t = 0.0f;                     // T_MIN pad
        if ((unsigned)yy < (unsigned)HT && (unsigned)xx < (unsigned)WD)
            t = tj[(((bb * HT) + yy) * WD + xx) * CH + ch];
        const uint32_t m = (uint32_t)(t * 8388608.0f);   // exact
        return (m << 8) | (uint32_t)k;
    };

    const uint32_t key0 = makeKey(lane);
    const uint32_t key1 = makeKey(lane + 64);
    const uint32_t key2 = (lane < 16) ? makeKey(lane + 128) : 0xFFFFFFFFu;

    // zero-time flags (t==0 <=> m==0); dummy key2 decodes nonzero -> not counted
    const bool isz0 = (key0 >> 8) == 0;
    const bool isz1 = (key1 >> 8) == 0;
    const bool isz2 = (key2 >> 8) == 0;
    const int z = __popcll(__ballot(isz0)) + __popcll(__ballot(isz1))
                + __popcll(__ballot(isz2));

    // two smallest NONZERO keys across the wave (zeros masked to 0xFFFFFFFF)
    uint32_t a = isz0 ? 0xFFFFFFFFu : key0;
    uint32_t b = isz1 ? 0xFFFFFFFFu : key1;
    uint32_t c2 = isz2 ? 0xFFFFFFFFu : key2;
    uint32_t lo = min(a, b), hi = max(a, b);
    uint32_t m1 = min(lo, c2);
    uint32_t m2 = min(hi, max(lo, c2));
    #pragma unroll
    for (int s = 1; s < 64; s <<= 1) {
        const uint32_t o1 = (uint32_t)__shfl_xor((int)m1, s);
        const uint32_t o2 = (uint32_t)__shfl_xor((int)m2, s);
        const uint32_t nl = min(m1, o1);
        const uint32_t nh = max(m1, o1);
        m2 = min(min(nh, m2), o2);
        m1 = nl;
    }

    const int   f   = lane & 15;
    const int   c   = lane >> 4;
    const float thr = threshold[f];
    const float al  = alpha[f];

    bool  fastOk;
    float ti_fast;

    if (z == 0) {
        // first sorted entry = m1; t_next = t of m2
        const float t1 = (float)(m1 >> 8) * INV23;
        const float t2 = (float)(m2 >> 8) * INV23;
        const float w  = kern[(m1 & 255u) * FT + f];
        const float numt = fmaf(w, t1, thr);      // == w*t1 when thr==0 (exact)
        const float dena = w + al;
        fastOk  = (dena > 0.0f) && (numt < t2 * dena);
        ti_fast = numt / dena;
    } else {
        // stage unsorted keys so each (f,c) lane can scan a 36-key chunk
        sKey[wave][lane]      = key0;
        sKey[wave][lane + 64] = key1;
        if (lane < 16) sKey[wave][lane + 128] = key2;

        float wsum = 0.0f;
        const uint4* kp = (const uint4*)(&sKey[wave][0]) + c * 9;
        #pragma unroll
        for (int j = 0; j < 9; ++j) {
            const uint4 kq = kp[j];
            const uint32_t ks[4] = {kq.x, kq.y, kq.z, kq.w};
            #pragma unroll
            for (int e = 0; e < 4; ++e) {
                const uint32_t kk = ks[e];
                if ((kk >> 8) == 0) wsum += kern[(kk & 255u) * FT + f];
            }
        }
        wsum += __shfl_xor(wsum, 16);
        wsum += __shfl_xor(wsum, 32);
        const float dena = wsum + al;
        const float tz   = (float)(m1 >> 8) * INV23;   // first nonzero t
        // candidate at end of zero block: num=0 -> numt=thr, valid iff
        // den>0 && thr < tz*den; thr>=0 guarantees earlier zeros are invalid
        fastOk  = (thr >= 0.0f) && (dena > 0.0f) && (thr < tz * dena);
        ti_fast = thr / dena;
    }

    if (__all(fastOk)) {
        if (lane < 16) {
            const float ti = ti_fast;
            out[n * FT + f] = (ti < 1.0f) ? ti : 1.0f;
        }
        return;
    }

    // ==================== fallback: full sort + scan =========================
    sKey[wave][lane]      = key0;
    sKey[wave][lane + 64] = key1;
    if (lane < 16) sKey[wave][lane + 128] = key2;

    int r0 = 0, r1 = 0, r2 = 0;
    {
        const uint4* kp = (const uint4*)(&sKey[wave][0]);
        #pragma unroll 6
        for (int j = 0; j < KK / 4; ++j) {
            const uint4 kj = kp[j];         // broadcast b128 read
            r0 += (kj.x < key0) + (kj.y < key0) + (kj.z < key0) + (kj.w < key0);
            r1 += (kj.x < key1) + (kj.y < key1) + (kj.z < key1) + (kj.w < key1);
            r2 += (kj.x < key2) + (kj.y < key2) + (kj.z < key2) + (kj.w < key2);
        }
    }
    sKey[wave][r0] = key0;
    sKey[wave][r1] = key1;
    if (lane < 16) sKey[wave][r2] = key2;

    // pass A: per-chunk partial sums (keys now sorted)
    float lN = 0.0f, lD = 0.0f;
    {
        const uint4* kp = (const uint4*)(&sKey[wave][0]) + c * 9;
        #pragma unroll
        for (int j = 0; j < 9; ++j) {
            const uint4 kq = kp[j];
            const uint32_t ks[4] = {kq.x, kq.y, kq.z, kq.w};
            #pragma unroll
            for (int e = 0; e < 4; ++e) {
                const uint32_t kk = ks[e];
                const float t = (float)(kk >> 8) * INV23;
                const float w = kern[(kk & 255u) * FT + f];
                lN = fmaf(w, t, lN);
                lD += w;
            }
        }
    }
    float iN = lN, iD = lD;
    {
        float sN = __shfl_up(iN, 16), sD = __shfl_up(iD, 16);
        if (c >= 1) { iN += sN; iD += sD; }
        sN = __shfl_up(iN, 32); sD = __shfl_up(iD, 32);
        if (c >= 2) { iN += sN; iD += sD; }
    }
    float num = iN - lN;    // exclusive prefix of cumsum(J*t)
    float den = iD - lD;    // exclusive prefix of cumsum(J)

    const int kbeg = c * 36;
    uint32_t ecur = sKey[wave][kbeg];
    float tbound = __shfl_down((float)((ecur >> 8)) * INV23, 16);
    if (c == 3) tbound = 1.0e6f;

    // pass B: first-valid select within chunk
    float selN = 0.0f, selD = 1.0f;
    bool  found = false;
    #pragma unroll 4
    for (int i = 0; i < 36; ++i) {
        uint32_t enext = 0;
        float tn;
        if (i < 35) { enext = sKey[wave][kbeg + i + 1]; tn = (float)(enext >> 8) * INV23; }
        else        { tn = tbound; }
        const float t = (float)(ecur >> 8) * INV23;
        const float w = kern[(ecur & 255u) * FT + f];
        num = fmaf(w, t, num);
        den += w;
        const float numt = num + thr;
        const float dena = den + al;
        const bool valid = (dena > 0.0f) && (numt < tn * dena);
        const bool take  = !found && (valid || (c == 0 && i == 0));
        if (take) { selN = numt; selD = dena; }
        found = found || valid;
        if (i < 35) ecur = enext;
    }
    int pos = found ? c : ((c == 0) ? 6 : 7);

    {
        int   opos = __shfl_xor(pos, 16);
        float oN   = __shfl_xor(selN, 16);
        float oD   = __shfl_xor(selD, 16);
        if (opos < pos) { pos = opos; selN = oN; selD = oD; }
        opos = __shfl_xor(pos, 32);
        oN   = __shfl_xor(selN, 32);
        oD   = __shfl_xor(selD, 32);
        if (opos < pos) { pos = opos; selN = oN; selD = oD; }
    }
    if (c == 0) {
        const float ti = selN / selD;
        out[n * FT + f] = (ti < 1.0f) ? ti : 1.0f;
    }
}

extern "C" void kernel_launch(void* const* d_in, const int* in_sizes, int n_in,
                              void* d_out, int out_size, void* d_ws, size_t ws_size,
                              hipStream_t stream) {
    const float* tj    = (const float*)d_in[0];
    const float* kern  = (const float*)d_in[1];
    const float* thr   = (const float*)d_in[2];
    const float* alpha = (const float*)d_in[3];
    float*       out   = (float*)d_out;

    const int npix   = in_sizes[0] / CH;                  // B*H*W = 12544
    const int blocks = (npix + WAVES - 1) / WAVES;        // 3136
    spiking_conv2d_kernel<<<blocks, THREADS, 0, stream>>>(tj, kern, thr, alpha, out, npix);
}